// Round 22
// baseline (177.416 us; speedup 1.0000x reference)
//
#include <hip/hip_runtime.h>
#include <math.h>

#define B_ 4
#define N_ 5000
#define K_ 16
#define L_ 3
#define F_ 2
#define E_ 32
#define D_ 64
#define H_ 4
#define BN_ (B_*N_)          /* 20000 */
#define NK_ (N_*K_)          /* 80000 */
#define BIG_ 1.0e9f
#define RS_ 68               /* padded LDS tile row stride (floats) */

typedef __attribute__((ext_vector_type(8))) short s8v;   // bf16x8 MFMA frag
typedef __attribute__((ext_vector_type(4))) float f4v;   // fp32x4 accum

union FU { uint4 u; s8v s; };

// ---------------- bf16 helpers ----------------------------------------------
__device__ __forceinline__ unsigned pack_bf16(float lo, float hi) {
    unsigned ul = __float_as_uint(lo);
    unsigned uh = __float_as_uint(hi);
    ul = (ul + 0x7fffu + ((ul >> 16) & 1u)) >> 16;
    uh = (uh + 0x7fffu + ((uh >> 16) & 1u)) & 0xffff0000u;
    return uh | ul;
}
__device__ __forceinline__ unsigned short f_to_bf16(float v) {
    unsigned u = __float_as_uint(v);
    return (unsigned short)((u + 0x7fffu + ((u >> 16) & 1u)) >> 16);
}
__device__ __forceinline__ float bf16_to_f(unsigned short u) {
    return __uint_as_float(((unsigned)u) << 16);
}

// ---------------- init: weight frag (0-11), acc zero (12), encoder (13..5012),
//                  neigh pack (5013..5052), adj pack (5053..5060) ------------
__global__ __launch_bounds__(256) void k_init(
    const float* __restrict__ Wq, const float* __restrict__ nbW,
    const float* __restrict__ Wk, const float* __restrict__ Wv,
    const float* __restrict__ Wo,
    const float* __restrict__ gWz, const float* __restrict__ gUz,
    const float* __restrict__ gWr, const float* __restrict__ gUr,
    const float* __restrict__ gWh, const float* __restrict__ gUh,
    const float* __restrict__ decW1, unsigned* __restrict__ pf,
    float* __restrict__ acc,
    const float* __restrict__ embed, const float* __restrict__ feat,
    const float* __restrict__ encW, const float* __restrict__ encb,
    float* __restrict__ h,
    const int* __restrict__ neigh, unsigned short* __restrict__ nb16,
    const int* __restrict__ adj, unsigned short* __restrict__ adj16)
{
    int m = blockIdx.x;
    if (m < 12) {
        const float* src = nullptr;
        switch (m) {
            case 0: src = Wq;  break; case 1: src = nbW; break;
            case 2: src = Wk;  break; case 3: src = Wv;  break;
            case 4: src = Wo;  break; case 5: src = gWz; break;
            case 6: src = gUz; break; case 7: src = gWr; break;
            case 8: src = gUr; break; case 9: src = gWh; break;
            case 10: src = gUh; break; default: break;
        }
        for (int j = threadIdx.x; j < 2048; j += 256) {
            int fgrp = j >> 8;
            int li = j & 255;
            int e2 = li >> 6;
            int lane = li & 63;
            int s = fgrp >> 2, w = fgrp & 3;
            int k = 32 * s + 8 * (lane >> 4) + 2 * e2;
            int c = 16 * w + (lane & 15);
            float v0, v1;
            if (m < 11) {
                v0 = src[k * 64 + c];
                v1 = src[(k + 1) * 64 + c];
            } else {
                v0 = (c < 32) ? decW1[k * 32 + c]       : decW1[(64 + k) * 32 + (c - 32)];
                v1 = (c < 32) ? decW1[(k + 1) * 32 + c] : decW1[(64 + k + 1) * 32 + (c - 32)];
            }
            pf[m * 2048 + fgrp * 256 + lane * 4 + e2] = pack_bf16(v0, v1);
        }
        return;
    }
    if (m == 12) {
        if (threadIdx.x < 192) acc[threadIdx.x] = 0.f;
        return;
    }
    if (m >= 5013 && m < 5053) {       // pack neigh: 40 blocks x 24000 entries
        int base = (m - 5013) * 24000;
        for (int i = threadIdx.x; i < 24000; i += 256)
            nb16[base + i] = (unsigned short)neigh[base + i];
        return;
    }
    if (m >= 5053) {                   // pack adj: 8 blocks x 40000 entries
        int base = (m - 5053) * 40000;
        for (int i = threadIdx.x; i < 40000; i += 256)
            adj16[base + i] = (unsigned short)adj[base + i];
        return;
    }
    // encoder: blocks 13..5012, 4 nodes per block
    int wave = threadIdx.x >> 6;
    int lane = threadIdx.x & 63;
    int node = (m - 13) * 4 + wave;        // b*N+n  in [0,20000)
    int n = node % N_;

    float e = (lane < E_) ? embed[(size_t)n * E_ + lane] : 0.f;
    float ss = e * e;
    #pragma unroll
    for (int mm = 32; mm >= 1; mm >>= 1) ss += __shfl_xor(ss, mm, 64);
    float scale = 1.f / fmaxf(sqrtf(ss), 1.f);

    float inval = (lane < E_) ? e * scale
                : (lane < E_ + F_) ? feat[(size_t)node * F_ + (lane - E_)]
                : 0.f;

    float a = encb[lane];
    #pragma unroll
    for (int i = 0; i < E_ + F_; ++i)
        a = fmaf(__shfl(inval, i, 64), encW[i * D_ + lane], a);
    h[(size_t)node * D_ + lane] = a;
}

// B-fragment read DIRECTLY from global pre-fragged pool (L2-resident, 96KB)
__device__ __forceinline__ s8v bfragG(const unsigned* __restrict__ pf,
                                      int m, int s, int w, int lane)
{
    FU f;
    f.u = *(const uint4*)&pf[m * 2048 + ((s * 4 + w) * 64 + lane) * 4];
    return f.s;
}

// A-fragment from fp32 tile (stride RS_): row=lane&15, k=32s+8*(lane>>4)+e
__device__ __forceinline__ s8v afragS(const float* T, int lane, int s)
{
    int row = lane & 15;
    int kb = 32 * s + 8 * (lane >> 4);
    float4 a = *(const float4*)&T[row * RS_ + kb];
    float4 b = *(const float4*)&T[row * RS_ + kb + 4];
    FU f;
    f.u.x = pack_bf16(a.x, a.y);
    f.u.y = pack_bf16(a.z, a.w);
    f.u.z = pack_bf16(b.x, b.y);
    f.u.w = pack_bf16(b.z, b.w);
    return f.s;
}

// D-layout write/read: col=16w+(lane&15), rows (lane>>4)*4+r
__device__ __forceinline__ void dwrite(float* T, int w, int lane, f4v d)
{
    int col = 16 * w + (lane & 15);
    int r0 = (lane >> 4) * 4;
    #pragma unroll
    for (int r = 0; r < 4; ++r) T[(r0 + r) * RS_ + col] = d[r];
}
__device__ __forceinline__ f4v dread(const float* T, int w, int lane)
{
    int col = 16 * w + (lane & 15);
    int r0 = (lane >> 4) * 4;
    f4v v;
    #pragma unroll
    for (int r = 0; r < 4; ++r) v[r] = T[(r0 + r) * RS_ + col];
    return v;
}

#define MFMA(a, b, c) __builtin_amdgcn_mfma_f32_16x16x32_bf16((a), (b), (c), 0, 0, 0)

// ================= fused graph layer (MFMA, global B-frags, XCD-swizzled) ===
__global__ __launch_bounds__(256, 5) void k_layer(
    const float* __restrict__ hin, float* __restrict__ hout,
    const unsigned short* __restrict__ nb16, const int* __restrict__ numn,
    const unsigned* __restrict__ pf,
    const float* __restrict__ gbz, const float* __restrict__ gbr,
    const float* __restrict__ gbh,
    float* __restrict__ Pout, unsigned short* __restrict__ Pn16, int last)
{
    __shared__ __align__(16) float sM[3][16 * RS_];    // mean->states; sM[0]->rh
    __shared__ __align__(16) float sH[16 * RS_];       // h tile (stable)
    __shared__ __align__(16) float sX[16 * RS_];       // ao -> x -> h'
    __shared__ int sIdx[3][256];

    int j = blockIdx.x;
    int xcd = j & 7, slot = j >> 3;
    int bb = xcd >> 1;                 // batch pinned to XCD pair
    int tile = slot * 2 + (xcd & 1);   // 0..319 within batch
    if (tile * 16 >= N_) return;       // idle tail blocks

    int tx = threadIdx.x;
    int wv = tx >> 6, lane = tx & 63;
    int row = tx >> 4, cg = tx & 15, c0 = cg * 4;
    int ln = tile * 16 + row;          // local node in batch
    bool act = ln < N_;
    int g = bb * N_ + (act ? ln : 0);  // clamped global node id
    int pad = numn[bb];
    const float4* hb4 = (const float4*)(hin + (size_t)bb * N_ * D_);

    // Ph0: h tile + neighbor ids (u16 table)
    float4 hld = act ? *(const float4*)&hin[(size_t)g * 64 + c0]
                     : make_float4(0.f, 0.f, 0.f, 0.f);
    *(float4*)&sH[row * RS_ + c0] = hld;
    #pragma unroll
    for (int t = 0; t < 3; ++t)
        sIdx[t][cg * 16 + row] =
            act ? (int)nb16[((size_t)t * BN_ + g) * K_ + cg] : pad;
    __syncthreads();                                           // B0

    // Ph1: q = h@Wq; gather means
    s8v hA0 = afragS(sH, lane, 0), hA1 = afragS(sH, lane, 1);
    f4v qD = {0.f, 0.f, 0.f, 0.f};
    qD = MFMA(hA0, bfragG(pf, 0, 0, wv, lane), qD);
    qD = MFMA(hA1, bfragG(pf, 0, 1, wv, lane), qD);

    #pragma unroll
    for (int t = 0; t < 3; ++t) {
        float4 s = make_float4(0.f, 0.f, 0.f, 0.f);
        int cnt = 0;
        #pragma unroll
        for (int k = 0; k < K_; ++k) {
            int idx = sIdx[t][k * 16 + row];
            if (idx != pad) {
                float4 v = hb4[(size_t)idx * 16 + cg];
                s.x += v.x; s.y += v.y; s.z += v.z; s.w += v.w;
                cnt++;
            }
        }
        float inv = 1.f / fmaxf((float)cnt, 1.f);
        *(float4*)&sM[t][row * RS_ + c0] =
            make_float4(s.x * inv, s.y * inv, s.z * inv, s.w * inv);
    }
    __syncthreads();                                           // B1

    // Ph2: read mean A-frags
    s8v mA[3][2];
    #pragma unroll
    for (int t = 0; t < 3; ++t) {
        mA[t][0] = afragS(sM[t], lane, 0);
        mA[t][1] = afragS(sM[t], lane, 1);
    }
    __syncthreads();                                           // B2

    // Ph3: states = tanh(mean@nbW) in-place
    {
        s8v nB0 = bfragG(pf, 1, 0, wv, lane), nB1 = bfragG(pf, 1, 1, wv, lane);
        #pragma unroll
        for (int t = 0; t < 3; ++t) {
            f4v d = {0.f, 0.f, 0.f, 0.f};
            d = MFMA(mA[t][0], nB0, d);
            d = MFMA(mA[t][1], nB1, d);
            #pragma unroll
            for (int r = 0; r < 4; ++r) d[r] = tanhf(d[r]);
            dwrite(sM[t], wv, lane, d);
        }
    }
    __syncthreads();                                           // B3

    // Ph4: kk/scores/softmax/vv/ao
    s8v stA[3][2];
    #pragma unroll
    for (int t = 0; t < 3; ++t) {
        stA[t][0] = afragS(sM[t], lane, 0);
        stA[t][1] = afragS(sM[t], lane, 1);
    }
    float sc[3][4];
    {
        s8v kB0 = bfragG(pf, 2, 0, wv, lane), kB1 = bfragG(pf, 2, 1, wv, lane);
        #pragma unroll
        for (int t = 0; t < 3; ++t) {
            f4v kk = {0.f, 0.f, 0.f, 0.f};
            kk = MFMA(stA[t][0], kB0, kk);
            kk = MFMA(stA[t][1], kB1, kk);
            float p0 = kk[0] * qD[0], p1 = kk[1] * qD[1];
            float p2 = kk[2] * qD[2], p3 = kk[3] * qD[3];
            #pragma unroll
            for (int m = 1; m < 16; m <<= 1) {
                p0 += __shfl_xor(p0, m, 64);
                p1 += __shfl_xor(p1, m, 64);
                p2 += __shfl_xor(p2, m, 64);
                p3 += __shfl_xor(p3, m, 64);
            }
            sc[t][0] = p0 * 0.25f; sc[t][1] = p1 * 0.25f;      // / sqrt(16)
            sc[t][2] = p2 * 0.25f; sc[t][3] = p3 * 0.25f;
        }
    }
    f4v w0v, w1v, w2v;
    #pragma unroll
    for (int r = 0; r < 4; ++r) {
        float p0 = sc[0][r], p1 = sc[1][r], p2 = sc[2][r];
        float mx = fmaxf(p0, fmaxf(p1, p2));
        float e0 = expf(p0 - mx), e1 = expf(p1 - mx), e2 = expf(p2 - mx);
        float inv = 1.f / (e0 + e1 + e2);
        w0v[r] = e0 * inv; w1v[r] = e1 * inv; w2v[r] = e2 * inv;
    }
    {
        s8v vB0 = bfragG(pf, 3, 0, wv, lane), vB1 = bfragG(pf, 3, 1, wv, lane);
        f4v vv0 = {0.f,0.f,0.f,0.f}, vv1 = {0.f,0.f,0.f,0.f}, vv2 = {0.f,0.f,0.f,0.f};
        vv0 = MFMA(stA[0][0], vB0, vv0); vv0 = MFMA(stA[0][1], vB1, vv0);
        vv1 = MFMA(stA[1][0], vB0, vv1); vv1 = MFMA(stA[1][1], vB1, vv1);
        vv2 = MFMA(stA[2][0], vB0, vv2); vv2 = MFMA(stA[2][1], vB1, vv2);
        f4v ao;
        #pragma unroll
        for (int r = 0; r < 4; ++r)
            ao[r] = w0v[r] * vv0[r] + w1v[r] * vv1[r] + w2v[r] * vv2[r];
        dwrite(sX, wv, lane, ao);
    }
    __syncthreads();                                           // B4

    // Ph5: read ao A-frags
    s8v aoA0 = afragS(sX, lane, 0), aoA1 = afragS(sX, lane, 1);
    __syncthreads();                                           // B5

    // Ph6: x = tanh(ao@Wo) in-place sX
    {
        f4v xd = {0.f, 0.f, 0.f, 0.f};
        xd = MFMA(aoA0, bfragG(pf, 4, 0, wv, lane), xd);
        xd = MFMA(aoA1, bfragG(pf, 4, 1, wv, lane), xd);
        #pragma unroll
        for (int r = 0; r < 4; ++r) xd[r] = tanhf(xd[r]);
        dwrite(sX, wv, lane, xd);
    }
    __syncthreads();                                           // B6

    // Ph7: x A-frags; gates; rh -> sM[0]
    s8v xA0 = afragS(sX, lane, 0), xA1 = afragS(sX, lane, 1);
    f4v az = {0.f, 0.f, 0.f, 0.f}, ar = {0.f, 0.f, 0.f, 0.f};
    az = MFMA(xA0, bfragG(pf, 5, 0, wv, lane), az);
    az = MFMA(xA1, bfragG(pf, 5, 1, wv, lane), az);
    az = MFMA(hA0, bfragG(pf, 6, 0, wv, lane), az);
    az = MFMA(hA1, bfragG(pf, 6, 1, wv, lane), az);
    ar = MFMA(xA0, bfragG(pf, 7, 0, wv, lane), ar);
    ar = MFMA(xA1, bfragG(pf, 7, 1, wv, lane), ar);
    ar = MFMA(hA0, bfragG(pf, 8, 0, wv, lane), ar);
    ar = MFMA(hA1, bfragG(pf, 8, 1, wv, lane), ar);
    int col = 16 * wv + (lane & 15);
    float bzv = gbz[col], brv = gbr[col];
    f4v hD = dread(sH, wv, lane);
    f4v zg, rh;
    #pragma unroll
    for (int r = 0; r < 4; ++r) {
        zg[r] = 1.f / (1.f + expf(-(az[r] + bzv)));
        float rr = 1.f / (1.f + expf(-(ar[r] + brv)));
        rh[r] = rr * hD[r];
    }
    dwrite(sM[0], wv, lane, rh);                               // stA reads done @B4
    __syncthreads();                                           // B7

    // Ph8: ah = x@gWh + rh@gUh; h' -> global (+ sX if last)
    s8v rhA0 = afragS(sM[0], lane, 0), rhA1 = afragS(sM[0], lane, 1);
    f4v ah = {0.f, 0.f, 0.f, 0.f};
    ah = MFMA(xA0, bfragG(pf, 9, 0, wv, lane), ah);
    ah = MFMA(xA1, bfragG(pf, 9, 1, wv, lane), ah);
    ah = MFMA(rhA0, bfragG(pf, 10, 0, wv, lane), ah);
    ah = MFMA(rhA1, bfragG(pf, 10, 1, wv, lane), ah);
    float bhv = gbh[col];
    int lr0 = (lane >> 4) * 4;
    int nodeb = bb * N_ + tile * 16;
    f4v hp;
    #pragma unroll
    for (int r = 0; r < 4; ++r) {
        float hh = tanhf(ah[r] + bhv);
        hp[r] = (1.f - zg[r]) * hD[r] + zg[r] * hh;
        if (tile * 16 + lr0 + r < N_)
            hout[(size_t)(nodeb + lr0 + r) * 64 + col] = hp[r];
    }

    if (last) {
        dwrite(sX, wv, lane, hp);                              // xA reads done @B7
        __syncthreads();                                       // B8
        s8v pA0 = afragS(sX, lane, 0), pA1 = afragS(sX, lane, 1);
        f4v pD = {0.f, 0.f, 0.f, 0.f};
        pD = MFMA(pA0, bfragG(pf, 11, 0, wv, lane), pD);
        pD = MFMA(pA1, bfragG(pf, 11, 1, wv, lane), pD);
        #pragma unroll
        for (int r = 0; r < 4; ++r) {
            if (tile * 16 + lr0 + r < N_) {
                Pout[(size_t)(nodeb + lr0 + r) * 64 + col] = pD[r];
                if (col >= 32)   // bf16 copy of the randomly-gathered nbr half
                    Pn16[(size_t)(nodeb + lr0 + r) * 32 + (col - 32)] = f_to_bf16(pD[r]);
            }
        }
    }
}

// ====== merged dual vars (blocks 0..499) + edge decoder (500..10499) ========
__global__ __launch_bounds__(256) void k_dec_dual(
    const float* __restrict__ P, const unsigned short* __restrict__ Pn16,
    const unsigned short* __restrict__ adj16,
    const float* __restrict__ b1, const float* __restrict__ W2,
    const float* __restrict__ b2, const int* __restrict__ num_nodes,
    float* __restrict__ nw,
    const float* __restrict__ h, const float* __restrict__ dW1,
    const float* __restrict__ db1, const float* __restrict__ dW2,
    const float* __restrict__ db2, const float* __restrict__ demands,
    float* __restrict__ dv, float* __restrict__ acc_out)
{
    __shared__ float sW1[D_ * 32];
    __shared__ float sW2[32];
    __shared__ float sPart[8];

    int blk = blockIdx.x;
    if (blk >= 500) {
        // ---- edge decoder, XCD-swizzled: 32 edges/block ----
        int dblk = blk - 500;
        int xcd = dblk & 7;
        int bb = xcd >> 1;
        int chunk = (dblk >> 3) * 2 + (xcd & 1);  // 0..2499 exact
        int half = threadIdx.x >> 5;
        int jj   = threadIdx.x & 31;
        float bias = b1[jj], w2 = W2[jj], b2v = b2[0];
        int pad = num_nodes[bb];
        const float* Pb = P + (size_t)bb * N_ * D_;
        const unsigned short* Pnb = Pn16 + (size_t)bb * N_ * 32;

        #pragma unroll
        for (int p = 0; p < 4; ++p) {
            int le = chunk * 32 + p * 8 + half;
            size_t e = (size_t)bb * NK_ + le;
            int lnode = le >> 4;
            int a = (int)adj16[e];
            float own = Pb[(size_t)lnode * D_ + jj];
            bool pd = (a == pad);
            float nbr = pd ? 0.f : bf16_to_f(Pnb[(size_t)(a == pad ? 0 : a) * 32 + jj]);
            float am = pd ? 0.f : 1.f;
            float t = tanhf(bias + am * own + am * nbr);
            float part = t * w2;
            #pragma unroll
            for (int m = 1; m < 32; m <<= 1) part += __shfl_xor(part, m, 64);
            if (jj == 0) nw[e] = part + b2v;
        }
        return;
    }

    // ---- dual vars: blocks 0..499 (40 nodes each) ----
    int bid = blk;
    for (int i = threadIdx.x; i < D_ * 32; i += 256) sW1[i] = dW1[i];
    if (threadIdx.x < 32) sW2[threadIdx.x] = dW2[threadIdx.x];
    __syncthreads();

    int half = threadIdx.x >> 5;
    int j    = threadIdx.x & 31;
    int b = (bid * 40) / N_;
    float bias = db1[j], b2v = db2[0];
    float local = 0.f;

    #pragma unroll 1
    for (int p = 0; p < 5; ++p) {
        int node = bid * 40 + p * 8 + half;
        const float* hp = h + (size_t)node * D_;
        float h0 = hp[j], h1 = hp[j + 32];
        float acc = bias;
        #pragma unroll 8
        for (int i = 0; i < 32; ++i) {
            acc = fmaf(__shfl(h0, i, 32), sW1[i * 32 + j],        acc);
            acc = fmaf(__shfl(h1, i, 32), sW1[(i + 32) * 32 + j], acc);
        }
        float t = tanhf(acc);
        float part = t * sW2[j];
        #pragma unroll
        for (int m = 1; m < 32; m <<= 1) part += __shfl_xor(part, m, 64);
        if (j == 0) {
            float v = part + b2v;
            dv[node] = v;
            local += v * demands[node];
        }
    }
    if (j == 0) sPart[half] = local;
    __syncthreads();
    if (threadIdx.x == 0) {
        float s = 0.f;
        #pragma unroll
        for (int i = 0; i < 8; ++i) s += sPart[i];
        atomicAdd(&acc_out[(b * 3 + 2) * 16], s);
    }
}

// ---------------- dest softmax over permuted groups (XCD-swizzled) ----------
__global__ void k_dest(
    const float* __restrict__ nw, const int* __restrict__ in_idx,
    const int* __restrict__ inv_adj, const int* __restrict__ num_nodes,
    float* __restrict__ dest)
{
    int j = blockIdx.x;
    int xcd = j & 7;
    int bb = xcd >> 1;
    int chunk = (j >> 3) * 2 + (xcd & 1);
    int ln = chunk * 256 + threadIdx.x;
    if (ln >= N_) return;
    int t = bb * N_ + ln;
    int pad = num_nodes[bb];
    float vals[K_]; float mx = -INFINITY;
    #pragma unroll
    for (int k = 0; k < K_; ++k) {
        int jj = in_idx[(size_t)t * K_ + k];
        float g = nw[(size_t)bb * NK_ + jj];
        float im = (inv_adj[(size_t)t * K_ + k] == pad) ? 1.f : 0.f;
        float v = g - BIG_ * im;
        vals[k] = v; mx = fmaxf(mx, v);
    }
    float s = 0.f;
    #pragma unroll
    for (int k = 0; k < K_; ++k) { vals[k] = expf(vals[k] - mx); s += vals[k]; }
    float invs = 1.f / s;
    #pragma unroll
    for (int k = 0; k < K_; ++k) dest[(size_t)t * K_ + k] = vals[k] * invs;
}

// ---------------- normalized_weights (XCD-swizzled) -------------------------
__global__ void k_normw(
    const float* __restrict__ nw, const float* __restrict__ dest,
    const int* __restrict__ rev, const unsigned short* __restrict__ adj16,
    const int* __restrict__ num_nodes,
    float* __restrict__ normw)
{
    int j = blockIdx.x;
    int xcd = j & 7;
    int bb = xcd >> 1;
    int chunk = (j >> 3) * 2 + (xcd & 1);
    int ln = chunk * 256 + threadIdx.x;
    if (ln >= N_) return;
    int t = bb * N_ + ln;
    int pad = num_nodes[bb];
    float vals[K_]; float mx = -INFINITY;
    #pragma unroll
    for (int k = 0; k < K_; ++k) {
        size_t e = (size_t)t * K_ + k;
        float v = nw[e] * dest[(size_t)bb * NK_ + rev[e]];
        float m = ((int)adj16[e] == pad) ? 1.f : 0.f;
        v -= BIG_ * m;
        vals[k] = v; mx = fmaxf(mx, v);
    }
    float s = 0.f;
    #pragma unroll
    for (int k = 0; k < K_; ++k) { vals[k] = expf(vals[k] - mx); s += vals[k]; }
    float invs = 1.f / s;
    #pragma unroll
    for (int k = 0; k < K_; ++k)
        normw[(size_t)t * K_ + k] = vals[k] * invs;
}

// ---------------- flow prep + ITERATION 1 (XCD-swizzled, u16 srcl) ----------
__global__ void k_prep(
    const float* __restrict__ normw, const int* __restrict__ in_idx,
    const int* __restrict__ inv_adj, const int* __restrict__ num_nodes,
    const float* __restrict__ demands,
    float* __restrict__ supply, float* __restrict__ wgt,
    unsigned short* __restrict__ srcl, float* __restrict__ tot1)
{
    int j = blockIdx.x;
    int xcd = j & 7;
    int bb = xcd >> 1;
    int chunk = (j >> 3) * 2 + (xcd & 1);
    int ln = chunk * 256 + threadIdx.x;
    if (ln >= N_) return;
    int t = bb * N_ + ln;
    int pad = num_nodes[bb];
    float sup = fmaxf(-demands[t], 0.f);
    supply[t] = sup;
    float s1 = sup;
    #pragma unroll
    for (int k = 0; k < K_; ++k) {
        size_t e = (size_t)t * K_ + k;
        int jj = in_idx[e];
        bool valid = (inv_adj[e] != pad);
        float w = valid ? normw[(size_t)bb * NK_ + jj] : 0.f;
        int sl = jj >> 4;                 // local source node
        wgt[e] = w;
        srcl[e] = (unsigned short)sl;
        s1 = fmaf(w, fmaxf(-demands[bb * N_ + sl], 0.f), s1);
    }
    tot1[t] = s1;
}

// ---------------- one tot-space flow step (XCD-swizzled, u16 srcl) ----------
__global__ void k_flowT(
    const float* __restrict__ totIn, const float* __restrict__ wgt,
    const unsigned short* __restrict__ srcl, const float* __restrict__ supply,
    float* __restrict__ totOut)
{
    int j = blockIdx.x;
    int xcd = j & 7;
    int bb = xcd >> 1;
    int chunk = (j >> 3) * 2 + (xcd & 1);
    int ln = chunk * 256 + threadIdx.x;
    if (ln >= N_) return;
    int t = bb * N_ + ln;
    const float* totb = totIn + (size_t)bb * N_;
    float s = supply[t];
    #pragma unroll
    for (int k = 0; k < K_; ++k) {
        size_t e = (size_t)t * K_ + k;
        s = fmaf(wgt[e], totb[srcl[e]], s);
    }
    totOut[t] = s;
}

// ---------------- dual iterations + costs (+ final flow step inline) --------
__global__ __launch_bounds__(256) void k_dualred(
    const float* __restrict__ el, const float* __restrict__ dv,
    const unsigned short* __restrict__ adj16, const int* __restrict__ num_nodes,
    const float* __restrict__ normw,
    const float* __restrict__ tot9, const float* __restrict__ wgt,
    const unsigned short* __restrict__ srcl, const float* __restrict__ supply,
    float* __restrict__ acc_out)
{
    int b = blockIdx.y;
    int ein = blockIdx.x * 256 + threadIdx.x;
    float c0 = 0.f, c1 = 0.f;
    if (ein < NK_) {                       // NK_ % 16 == 0: groups never straddle
        size_t e = (size_t)b * NK_ + ein;
        int pad = num_nodes[b];
        int node = b * N_ + (ein >> 4);
        int a = (int)adj16[e];
        float am = (a == pad) ? 0.f : 1.f;
        float dtr = (a == pad) ? 0.f : dv[(size_t)b * N_ + a];
        float d = dtr - am * dv[node];
        float l = el[e];
        float f = 0.f, ac = 0.f;
        #pragma unroll
        for (int it = 0; it < 10; ++it) {
            float g = 2.f * l * f + d;
            ac = 0.9f * ac + 0.01f * g;
            f = fmaxf(f - ac, 0.f) * am;
        }
        // inline flow step 10: this edge's k-slot contribution
        float part = wgt[e] * tot9[(size_t)b * N_ + srcl[e]];
        #pragma unroll
        for (int m = 1; m < 16; m <<= 1) part += __shfl_xor(part, m, 64);
        float tot10 = supply[node] + part;
        float fl = normw[e] * tot10;
        c0 = l * fl * fl;          // flow_cost term
        c1 = l * f * f + d * f;    // dual flow term
    }
    #pragma unroll
    for (int m = 1; m < 64; m <<= 1) { c0 += __shfl_xor(c0, m, 64); c1 += __shfl_xor(c1, m, 64); }
    __shared__ float s0[4], s1[4];
    int wave = threadIdx.x >> 6, lane = threadIdx.x & 63;
    if (lane == 0) { s0[wave] = c0; s1[wave] = c1; }
    __syncthreads();
    if (threadIdx.x == 0) {
        atomicAdd(&acc_out[(b * 3 + 0) * 16], s0[0] + s0[1] + s0[2] + s0[3]);
        atomicAdd(&acc_out[(b * 3 + 1) * 16], s1[0] + s1[1] + s1[2] + s1[3]);
    }
}

// ---------------- finalize --------------------------------------------------
__global__ void k_final(const float* __restrict__ acc, float* __restrict__ out) {
    int b = threadIdx.x;
    if (b < B_)
        out[b] = acc[(b * 3 + 0) * 16] - acc[(b * 3 + 1) * 16] + acc[(b * 3 + 2) * 16];
}

extern "C" void kernel_launch(void* const* d_in, const int* in_sizes, int n_in,
                              void* d_out, int out_size, void* d_ws, size_t ws_size,
                              hipStream_t stream)
{
    const float* demands = (const float*)d_in[0];
    const float* feat    = (const float*)d_in[1];
    const float* el      = (const float*)d_in[2];
    const float* embed   = (const float*)d_in[3];
    const float* encW    = (const float*)d_in[4];
    const float* encb    = (const float*)d_in[5];
    const float* nbW     = (const float*)d_in[6];
    const float* Wq      = (const float*)d_in[7];
    const float* Wk      = (const float*)d_in[8];
    const float* Wv      = (const float*)d_in[9];
    const float* Wo      = (const float*)d_in[10];
    const float* gWz     = (const float*)d_in[11];
    const float* gUz     = (const float*)d_in[12];
    const float* gbz     = (const float*)d_in[13];
    const float* gWr     = (const float*)d_in[14];
    const float* gUr     = (const float*)d_in[15];
    const float* gbr     = (const float*)d_in[16];
    const float* gWh     = (const float*)d_in[17];
    const float* gUh     = (const float*)d_in[18];
    const float* gbh     = (const float*)d_in[19];
    const float* decW1   = (const float*)d_in[20];
    const float* decb1   = (const float*)d_in[21];
    const float* decW2   = (const float*)d_in[22];
    const float* decb2   = (const float*)d_in[23];
    const float* dualW1  = (const float*)d_in[24];
    const float* dualb1  = (const float*)d_in[25];
    const float* dualW2  = (const float*)d_in[26];
    const float* dualb2  = (const float*)d_in[27];
    const int* adj       = (const int*)d_in[28];
    const int* invadj    = (const int*)d_in[29];
    const int* neigh     = (const int*)d_in[30];
    const int* inidx     = (const int*)d_in[31];
    const int* revidx    = (const int*)d_in[32];
    const int* numn      = (const int*)d_in[33];

    // workspace (floats), ~27MB
    float* ws     = (float*)d_ws;
    float* h0     = ws;                   // 1,280,000
    float* h1     = ws + 1280000;         // 1,280,000 (ping-pong)
    float* nw     = ws + 2560000;         // 320,000
    float* dest   = ws + 2880000;         // 320,000
    float* normw  = ws + 3200000;         // 320,000
    float* wgt    = ws + 3520000;         // 320,000
    unsigned short* srcl = (unsigned short*)(ws + 3840000); // 320,000 u16
    float* totA   = ws + 4160000;         // 20,000
    float* totB   = ws + 4180000;         // 20,000
    float* supply = ws + 4200000;         // 20,000
    float* dv     = ws + 4220000;         // 20,000
    float* acc    = ws + 4240000;         // 192
    float* P      = ws + 4250000;         // 1,280,000 (edge projections)
    unsigned* pf  = (unsigned*)(ws + 5540000);              // 24,576 u32
    unsigned short* Pn16 = (unsigned short*)(ws + 5570000); // 640,000 u16
    unsigned short* nb16 = (unsigned short*)(ws + 5890000); // 960,000 u16
    unsigned short* adj16 = (unsigned short*)(ws + 6370000);// 320,000 u16

    // init: prepW (0-11), acc zero (12), encoder (13..5012),
    //       neigh pack (5013..5052), adj pack (5053..5060)
    k_init<<<5061, 256, 0, stream>>>(Wq, nbW, Wk, Wv, Wo, gWz, gUz,
                                     gWr, gUr, gWh, gUh, decW1, pf, acc,
                                     embed, feat, encW, encb, h0,
                                     neigh, nb16, adj, adj16);

    // layer 0: h0 -> h1 ; layer 1: h1 -> h0 (+ P/Pn16); XCD-swizzled grid
    k_layer<<<1280, 256, 0, stream>>>(h0, h1, nb16, numn, pf,
                                      gbz, gbr, gbh, P, Pn16, 0);
    k_layer<<<1280, 256, 0, stream>>>(h1, h0, nb16, numn, pf,
                                      gbz, gbr, gbh, P, Pn16, 1);
    float* h = h0;

    k_dec_dual<<<10500, 256, 0, stream>>>(P, Pn16, adj16, decb1, decW2, decb2,
                                          numn, nw,
                                          h, dualW1, dualb1, dualW2, dualb2,
                                          demands, dv, acc);
    k_dest<<<80, 256, 0, stream>>>(nw, inidx, invadj, numn, dest);
    k_normw<<<80, 256, 0, stream>>>(nw, dest, revidx, adj16, numn, normw);
    k_prep<<<80, 256, 0, stream>>>(normw, inidx, invadj, numn, demands,
                                   supply, wgt, srcl, totA);

    // totA holds tot1; 8 more launched iterations -> tot9 ends in totA
    float* cur = totA; float* nxt = totB;
    for (int it = 0; it < 8; ++it) {
        k_flowT<<<80, 256, 0, stream>>>(cur, wgt, srcl, supply, nxt);
        float* tmp = cur; cur = nxt; nxt = tmp;
    }

    // iteration 10 fused into dualred (16-lane group reduce)
    dim3 gred((NK_ + 255) / 256, B_);
    k_dualred<<<gred, 256, 0, stream>>>(el, dv, adj16, numn, normw,
                                        cur, wgt, srcl, supply, acc);
    k_final<<<1, 64, 0, stream>>>(acc, (float*)d_out);
}

// Round 23
// 160.585 us; speedup vs baseline: 1.1048x; 1.1048x over previous
//
#include <hip/hip_runtime.h>
#include <math.h>

#define B_ 4
#define N_ 5000
#define K_ 16
#define L_ 3
#define F_ 2
#define E_ 32
#define D_ 64
#define H_ 4
#define BN_ (B_*N_)          /* 20000 */
#define NK_ (N_*K_)          /* 80000 */
#define BIG_ 1.0e9f
#define RS_ 68               /* padded LDS tile row stride (floats) */

typedef __attribute__((ext_vector_type(8))) short s8v;   // bf16x8 MFMA frag
typedef __attribute__((ext_vector_type(4))) float f4v;   // fp32x4 accum

union FU { uint4 u; s8v s; };

// ---------------- bf16 helpers ----------------------------------------------
__device__ __forceinline__ unsigned pack_bf16(float lo, float hi) {
    unsigned ul = __float_as_uint(lo);
    unsigned uh = __float_as_uint(hi);
    ul = (ul + 0x7fffu + ((ul >> 16) & 1u)) >> 16;
    uh = (uh + 0x7fffu + ((uh >> 16) & 1u)) & 0xffff0000u;
    return uh | ul;
}
__device__ __forceinline__ unsigned short f_to_bf16(float v) {
    unsigned u = __float_as_uint(v);
    return (unsigned short)((u + 0x7fffu + ((u >> 16) & 1u)) >> 16);
}
__device__ __forceinline__ float bf16_to_f(unsigned short u) {
    return __uint_as_float(((unsigned)u) << 16);
}

// ---------------- init: weight frag (blocks 0-11), acc zero (12),
//                  encoder (blocks 13+) -------------------------------------
__global__ __launch_bounds__(256) void k_init(
    const float* __restrict__ Wq, const float* __restrict__ nbW,
    const float* __restrict__ Wk, const float* __restrict__ Wv,
    const float* __restrict__ Wo,
    const float* __restrict__ gWz, const float* __restrict__ gUz,
    const float* __restrict__ gWr, const float* __restrict__ gUr,
    const float* __restrict__ gWh, const float* __restrict__ gUh,
    const float* __restrict__ decW1, unsigned* __restrict__ pf,
    float* __restrict__ acc,
    const float* __restrict__ embed, const float* __restrict__ feat,
    const float* __restrict__ encW, const float* __restrict__ encb,
    float* __restrict__ h)
{
    int m = blockIdx.x;
    if (m < 12) {
        const float* src = nullptr;
        switch (m) {
            case 0: src = Wq;  break; case 1: src = nbW; break;
            case 2: src = Wk;  break; case 3: src = Wv;  break;
            case 4: src = Wo;  break; case 5: src = gWz; break;
            case 6: src = gUz; break; case 7: src = gWr; break;
            case 8: src = gUr; break; case 9: src = gWh; break;
            case 10: src = gUh; break; default: break;
        }
        for (int j = threadIdx.x; j < 2048; j += 256) {
            int fgrp = j >> 8;
            int li = j & 255;
            int e2 = li >> 6;
            int lane = li & 63;
            int s = fgrp >> 2, w = fgrp & 3;
            int k = 32 * s + 8 * (lane >> 4) + 2 * e2;
            int c = 16 * w + (lane & 15);
            float v0, v1;
            if (m < 11) {
                v0 = src[k * 64 + c];
                v1 = src[(k + 1) * 64 + c];
            } else {
                v0 = (c < 32) ? decW1[k * 32 + c]       : decW1[(64 + k) * 32 + (c - 32)];
                v1 = (c < 32) ? decW1[(k + 1) * 32 + c] : decW1[(64 + k + 1) * 32 + (c - 32)];
            }
            pf[m * 2048 + fgrp * 256 + lane * 4 + e2] = pack_bf16(v0, v1);
        }
        return;
    }
    if (m == 12) {
        if (threadIdx.x < 192) acc[threadIdx.x] = 0.f;
        return;
    }
    // encoder: blocks 13..13+4999, 4 nodes per block
    int wave = threadIdx.x >> 6;
    int lane = threadIdx.x & 63;
    int node = (m - 13) * 4 + wave;        // b*N+n  in [0,20000)
    int n = node % N_;

    float e = (lane < E_) ? embed[(size_t)n * E_ + lane] : 0.f;
    float ss = e * e;
    #pragma unroll
    for (int mm = 32; mm >= 1; mm >>= 1) ss += __shfl_xor(ss, mm, 64);
    float scale = 1.f / fmaxf(sqrtf(ss), 1.f);

    float inval = (lane < E_) ? e * scale
                : (lane < E_ + F_) ? feat[(size_t)node * F_ + (lane - E_)]
                : 0.f;

    float a = encb[lane];
    #pragma unroll
    for (int i = 0; i < E_ + F_; ++i)
        a = fmaf(__shfl(inval, i, 64), encW[i * D_ + lane], a);
    h[(size_t)node * D_ + lane] = a;
}

// B-fragment read DIRECTLY from global pre-fragged pool (L2-resident, 96KB)
__device__ __forceinline__ s8v bfragG(const unsigned* __restrict__ pf,
                                      int m, int s, int w, int lane)
{
    FU f;
    f.u = *(const uint4*)&pf[m * 2048 + ((s * 4 + w) * 64 + lane) * 4];
    return f.s;
}

// A-fragment from fp32 tile (stride RS_): row=lane&15, k=32s+8*(lane>>4)+e
__device__ __forceinline__ s8v afragS(const float* T, int lane, int s)
{
    int row = lane & 15;
    int kb = 32 * s + 8 * (lane >> 4);
    float4 a = *(const float4*)&T[row * RS_ + kb];
    float4 b = *(const float4*)&T[row * RS_ + kb + 4];
    FU f;
    f.u.x = pack_bf16(a.x, a.y);
    f.u.y = pack_bf16(a.z, a.w);
    f.u.z = pack_bf16(b.x, b.y);
    f.u.w = pack_bf16(b.z, b.w);
    return f.s;
}

// D-layout write/read: col=16w+(lane&15), rows (lane>>4)*4+r
__device__ __forceinline__ void dwrite(float* T, int w, int lane, f4v d)
{
    int col = 16 * w + (lane & 15);
    int r0 = (lane >> 4) * 4;
    #pragma unroll
    for (int r = 0; r < 4; ++r) T[(r0 + r) * RS_ + col] = d[r];
}
__device__ __forceinline__ f4v dread(const float* T, int w, int lane)
{
    int col = 16 * w + (lane & 15);
    int r0 = (lane >> 4) * 4;
    f4v v;
    #pragma unroll
    for (int r = 0; r < 4; ++r) v[r] = T[(r0 + r) * RS_ + col];
    return v;
}

#define MFMA(a, b, c) __builtin_amdgcn_mfma_f32_16x16x32_bf16((a), (b), (c), 0, 0, 0)

// ================= fused graph layer (MFMA, global B-frags, XCD-swizzled) ===
__global__ __launch_bounds__(256, 5) void k_layer(
    const float* __restrict__ hin, float* __restrict__ hout,
    const int* __restrict__ neigh, const int* __restrict__ numn,
    const unsigned* __restrict__ pf,
    const float* __restrict__ gbz, const float* __restrict__ gbr,
    const float* __restrict__ gbh,
    float* __restrict__ Pout, unsigned short* __restrict__ Pn16, int last)
{
    __shared__ __align__(16) float sM[3][16 * RS_];    // mean->states; sM[0]->rh
    __shared__ __align__(16) float sH[16 * RS_];       // h tile (stable)
    __shared__ __align__(16) float sX[16 * RS_];       // ao -> x -> h'
    __shared__ int sIdx[3][256];

    int j = blockIdx.x;
    int xcd = j & 7, slot = j >> 3;
    int bb = xcd >> 1;                 // batch pinned to XCD pair
    int tile = slot * 2 + (xcd & 1);   // 0..319 within batch
    if (tile * 16 >= N_) return;       // idle tail blocks

    int tx = threadIdx.x;
    int wv = tx >> 6, lane = tx & 63;
    int row = tx >> 4, cg = tx & 15, c0 = cg * 4;
    int ln = tile * 16 + row;          // local node in batch
    bool act = ln < N_;
    int g = bb * N_ + (act ? ln : 0);  // clamped global node id
    int pad = numn[bb];
    const float4* hb4 = (const float4*)(hin + (size_t)bb * N_ * D_);

    // Ph0: h tile + neighbor ids
    float4 hld = act ? *(const float4*)&hin[(size_t)g * 64 + c0]
                     : make_float4(0.f, 0.f, 0.f, 0.f);
    *(float4*)&sH[row * RS_ + c0] = hld;
    #pragma unroll
    for (int t = 0; t < 3; ++t)
        sIdx[t][cg * 16 + row] = act ? neigh[((size_t)t * BN_ + g) * K_ + cg] : pad;
    __syncthreads();                                           // B0

    // Ph1: q = h@Wq; gather means
    s8v hA0 = afragS(sH, lane, 0), hA1 = afragS(sH, lane, 1);
    f4v qD = {0.f, 0.f, 0.f, 0.f};
    qD = MFMA(hA0, bfragG(pf, 0, 0, wv, lane), qD);
    qD = MFMA(hA1, bfragG(pf, 0, 1, wv, lane), qD);

    #pragma unroll
    for (int t = 0; t < 3; ++t) {
        float4 s = make_float4(0.f, 0.f, 0.f, 0.f);
        int cnt = 0;
        #pragma unroll
        for (int k = 0; k < K_; ++k) {
            int idx = sIdx[t][k * 16 + row];
            if (idx != pad) {
                float4 v = hb4[(size_t)idx * 16 + cg];
                s.x += v.x; s.y += v.y; s.z += v.z; s.w += v.w;
                cnt++;
            }
        }
        float inv = 1.f / fmaxf((float)cnt, 1.f);
        *(float4*)&sM[t][row * RS_ + c0] =
            make_float4(s.x * inv, s.y * inv, s.z * inv, s.w * inv);
    }
    __syncthreads();                                           // B1

    // Ph2: read mean A-frags
    s8v mA[3][2];
    #pragma unroll
    for (int t = 0; t < 3; ++t) {
        mA[t][0] = afragS(sM[t], lane, 0);
        mA[t][1] = afragS(sM[t], lane, 1);
    }
    __syncthreads();                                           // B2

    // Ph3: states = tanh(mean@nbW) in-place
    {
        s8v nB0 = bfragG(pf, 1, 0, wv, lane), nB1 = bfragG(pf, 1, 1, wv, lane);
        #pragma unroll
        for (int t = 0; t < 3; ++t) {
            f4v d = {0.f, 0.f, 0.f, 0.f};
            d = MFMA(mA[t][0], nB0, d);
            d = MFMA(mA[t][1], nB1, d);
            #pragma unroll
            for (int r = 0; r < 4; ++r) d[r] = tanhf(d[r]);
            dwrite(sM[t], wv, lane, d);
        }
    }
    __syncthreads();                                           // B3

    // Ph4: kk/scores/softmax/vv/ao
    s8v stA[3][2];
    #pragma unroll
    for (int t = 0; t < 3; ++t) {
        stA[t][0] = afragS(sM[t], lane, 0);
        stA[t][1] = afragS(sM[t], lane, 1);
    }
    float sc[3][4];
    {
        s8v kB0 = bfragG(pf, 2, 0, wv, lane), kB1 = bfragG(pf, 2, 1, wv, lane);
        #pragma unroll
        for (int t = 0; t < 3; ++t) {
            f4v kk = {0.f, 0.f, 0.f, 0.f};
            kk = MFMA(stA[t][0], kB0, kk);
            kk = MFMA(stA[t][1], kB1, kk);
            float p0 = kk[0] * qD[0], p1 = kk[1] * qD[1];
            float p2 = kk[2] * qD[2], p3 = kk[3] * qD[3];
            #pragma unroll
            for (int m = 1; m < 16; m <<= 1) {
                p0 += __shfl_xor(p0, m, 64);
                p1 += __shfl_xor(p1, m, 64);
                p2 += __shfl_xor(p2, m, 64);
                p3 += __shfl_xor(p3, m, 64);
            }
            sc[t][0] = p0 * 0.25f; sc[t][1] = p1 * 0.25f;      // / sqrt(16)
            sc[t][2] = p2 * 0.25f; sc[t][3] = p3 * 0.25f;
        }
    }
    f4v w0v, w1v, w2v;
    #pragma unroll
    for (int r = 0; r < 4; ++r) {
        float p0 = sc[0][r], p1 = sc[1][r], p2 = sc[2][r];
        float mx = fmaxf(p0, fmaxf(p1, p2));
        float e0 = expf(p0 - mx), e1 = expf(p1 - mx), e2 = expf(p2 - mx);
        float inv = 1.f / (e0 + e1 + e2);
        w0v[r] = e0 * inv; w1v[r] = e1 * inv; w2v[r] = e2 * inv;
    }
    {
        s8v vB0 = bfragG(pf, 3, 0, wv, lane), vB1 = bfragG(pf, 3, 1, wv, lane);
        f4v vv0 = {0.f,0.f,0.f,0.f}, vv1 = {0.f,0.f,0.f,0.f}, vv2 = {0.f,0.f,0.f,0.f};
        vv0 = MFMA(stA[0][0], vB0, vv0); vv0 = MFMA(stA[0][1], vB1, vv0);
        vv1 = MFMA(stA[1][0], vB0, vv1); vv1 = MFMA(stA[1][1], vB1, vv1);
        vv2 = MFMA(stA[2][0], vB0, vv2); vv2 = MFMA(stA[2][1], vB1, vv2);
        f4v ao;
        #pragma unroll
        for (int r = 0; r < 4; ++r)
            ao[r] = w0v[r] * vv0[r] + w1v[r] * vv1[r] + w2v[r] * vv2[r];
        dwrite(sX, wv, lane, ao);
    }
    __syncthreads();                                           // B4

    // Ph5: read ao A-frags
    s8v aoA0 = afragS(sX, lane, 0), aoA1 = afragS(sX, lane, 1);
    __syncthreads();                                           // B5

    // Ph6: x = tanh(ao@Wo) in-place sX
    {
        f4v xd = {0.f, 0.f, 0.f, 0.f};
        xd = MFMA(aoA0, bfragG(pf, 4, 0, wv, lane), xd);
        xd = MFMA(aoA1, bfragG(pf, 4, 1, wv, lane), xd);
        #pragma unroll
        for (int r = 0; r < 4; ++r) xd[r] = tanhf(xd[r]);
        dwrite(sX, wv, lane, xd);
    }
    __syncthreads();                                           // B6

    // Ph7: x A-frags; gates; rh -> sM[0]
    s8v xA0 = afragS(sX, lane, 0), xA1 = afragS(sX, lane, 1);
    f4v az = {0.f, 0.f, 0.f, 0.f}, ar = {0.f, 0.f, 0.f, 0.f};
    az = MFMA(xA0, bfragG(pf, 5, 0, wv, lane), az);
    az = MFMA(xA1, bfragG(pf, 5, 1, wv, lane), az);
    az = MFMA(hA0, bfragG(pf, 6, 0, wv, lane), az);
    az = MFMA(hA1, bfragG(pf, 6, 1, wv, lane), az);
    ar = MFMA(xA0, bfragG(pf, 7, 0, wv, lane), ar);
    ar = MFMA(xA1, bfragG(pf, 7, 1, wv, lane), ar);
    ar = MFMA(hA0, bfragG(pf, 8, 0, wv, lane), ar);
    ar = MFMA(hA1, bfragG(pf, 8, 1, wv, lane), ar);
    int col = 16 * wv + (lane & 15);
    float bzv = gbz[col], brv = gbr[col];
    f4v hD = dread(sH, wv, lane);
    f4v zg, rh;
    #pragma unroll
    for (int r = 0; r < 4; ++r) {
        zg[r] = 1.f / (1.f + expf(-(az[r] + bzv)));
        float rr = 1.f / (1.f + expf(-(ar[r] + brv)));
        rh[r] = rr * hD[r];
    }
    dwrite(sM[0], wv, lane, rh);                               // stA reads done @B4
    __syncthreads();                                           // B7

    // Ph8: ah = x@gWh + rh@gUh; h' -> global (+ sX if last)
    s8v rhA0 = afragS(sM[0], lane, 0), rhA1 = afragS(sM[0], lane, 1);
    f4v ah = {0.f, 0.f, 0.f, 0.f};
    ah = MFMA(xA0, bfragG(pf, 9, 0, wv, lane), ah);
    ah = MFMA(xA1, bfragG(pf, 9, 1, wv, lane), ah);
    ah = MFMA(rhA0, bfragG(pf, 10, 0, wv, lane), ah);
    ah = MFMA(rhA1, bfragG(pf, 10, 1, wv, lane), ah);
    float bhv = gbh[col];
    int lr0 = (lane >> 4) * 4;
    int nodeb = bb * N_ + tile * 16;
    f4v hp;
    #pragma unroll
    for (int r = 0; r < 4; ++r) {
        float hh = tanhf(ah[r] + bhv);
        hp[r] = (1.f - zg[r]) * hD[r] + zg[r] * hh;
        if (tile * 16 + lr0 + r < N_)
            hout[(size_t)(nodeb + lr0 + r) * 64 + col] = hp[r];
    }

    if (last) {
        dwrite(sX, wv, lane, hp);                              // xA reads done @B7
        __syncthreads();                                       // B8
        s8v pA0 = afragS(sX, lane, 0), pA1 = afragS(sX, lane, 1);
        f4v pD = {0.f, 0.f, 0.f, 0.f};
        pD = MFMA(pA0, bfragG(pf, 11, 0, wv, lane), pD);
        pD = MFMA(pA1, bfragG(pf, 11, 1, wv, lane), pD);
        #pragma unroll
        for (int r = 0; r < 4; ++r) {
            if (tile * 16 + lr0 + r < N_) {
                Pout[(size_t)(nodeb + lr0 + r) * 64 + col] = pD[r];
                if (col >= 32)   // bf16 copy of the randomly-gathered nbr half
                    Pn16[(size_t)(nodeb + lr0 + r) * 32 + (col - 32)] = f_to_bf16(pD[r]);
            }
        }
    }
}

// ====== merged dual vars (blocks 0..499) + edge decoder (500..10499) ========
// dualvars first so it overlaps the decoder wave instead of tailing it.
// decoder nbr gather reads bf16 Pn16 (64B/row) -> half the random HBM bytes.
__global__ __launch_bounds__(256) void k_dec_dual(
    const float* __restrict__ P, const unsigned short* __restrict__ Pn16,
    const int* __restrict__ adj,
    const float* __restrict__ b1, const float* __restrict__ W2,
    const float* __restrict__ b2, const int* __restrict__ num_nodes,
    float* __restrict__ nw,
    const float* __restrict__ h, const float* __restrict__ dW1,
    const float* __restrict__ db1, const float* __restrict__ dW2,
    const float* __restrict__ db2, const float* __restrict__ demands,
    float* __restrict__ dv, float* __restrict__ acc_out)
{
    __shared__ float sW1[D_ * 32];
    __shared__ float sW2[32];
    __shared__ float sPart[8];

    int blk = blockIdx.x;
    if (blk >= 500) {
        // ---- edge decoder, XCD-swizzled: 32 edges/block ----
        int dblk = blk - 500;
        int xcd = dblk & 7;
        int bb = xcd >> 1;
        int chunk = (dblk >> 3) * 2 + (xcd & 1);  // 0..2499 exact
        int half = threadIdx.x >> 5;
        int jj   = threadIdx.x & 31;
        float bias = b1[jj], w2 = W2[jj], b2v = b2[0];
        int pad = num_nodes[bb];
        const float* Pb = P + (size_t)bb * N_ * D_;
        const unsigned short* Pnb = Pn16 + (size_t)bb * N_ * 32;

        #pragma unroll
        for (int p = 0; p < 4; ++p) {
            int le = chunk * 32 + p * 8 + half;
            size_t e = (size_t)bb * NK_ + le;
            int lnode = le >> 4;
            int a = adj[e];
            float own = Pb[(size_t)lnode * D_ + jj];
            bool pd = (a == pad);
            float nbr = pd ? 0.f : bf16_to_f(Pnb[(size_t)(a == pad ? 0 : a) * 32 + jj]);
            float am = pd ? 0.f : 1.f;
            float t = tanhf(bias + am * own + am * nbr);
            float part = t * w2;
            #pragma unroll
            for (int m = 1; m < 32; m <<= 1) part += __shfl_xor(part, m, 64);
            if (jj == 0) nw[e] = part + b2v;
        }
        return;
    }

    // ---- dual vars: blocks 0..499 (40 nodes each) ----
    int bid = blk;
    for (int i = threadIdx.x; i < D_ * 32; i += 256) sW1[i] = dW1[i];
    if (threadIdx.x < 32) sW2[threadIdx.x] = dW2[threadIdx.x];
    __syncthreads();

    int half = threadIdx.x >> 5;
    int j    = threadIdx.x & 31;
    int b = (bid * 40) / N_;
    float bias = db1[j], b2v = db2[0];
    float local = 0.f;

    #pragma unroll 1
    for (int p = 0; p < 5; ++p) {
        int node = bid * 40 + p * 8 + half;
        const float* hp = h + (size_t)node * D_;
        float h0 = hp[j], h1 = hp[j + 32];
        float acc = bias;
        #pragma unroll 8
        for (int i = 0; i < 32; ++i) {
            acc = fmaf(__shfl(h0, i, 32), sW1[i * 32 + j],        acc);
            acc = fmaf(__shfl(h1, i, 32), sW1[(i + 32) * 32 + j], acc);
        }
        float t = tanhf(acc);
        float part = t * sW2[j];
        #pragma unroll
        for (int m = 1; m < 32; m <<= 1) part += __shfl_xor(part, m, 64);
        if (j == 0) {
            float v = part + b2v;
            dv[node] = v;
            local += v * demands[node];
        }
    }
    if (j == 0) sPart[half] = local;
    __syncthreads();
    if (threadIdx.x == 0) {
        float s = 0.f;
        #pragma unroll
        for (int i = 0; i < 8; ++i) s += sPart[i];
        atomicAdd(&acc_out[(b * 3 + 2) * 16], s);
    }
}

// ---------------- dest softmax over permuted groups (XCD-swizzled) ----------
__global__ void k_dest(
    const float* __restrict__ nw, const int* __restrict__ in_idx,
    const int* __restrict__ inv_adj, const int* __restrict__ num_nodes,
    float* __restrict__ dest)
{
    int j = blockIdx.x;
    int xcd = j & 7;
    int bb = xcd >> 1;
    int chunk = (j >> 3) * 2 + (xcd & 1);
    int ln = chunk * 256 + threadIdx.x;
    if (ln >= N_) return;
    int t = bb * N_ + ln;
    int pad = num_nodes[bb];
    float vals[K_]; float mx = -INFINITY;
    #pragma unroll
    for (int k = 0; k < K_; ++k) {
        int jj = in_idx[(size_t)t * K_ + k];
        float g = nw[(size_t)bb * NK_ + jj];
        float im = (inv_adj[(size_t)t * K_ + k] == pad) ? 1.f : 0.f;
        float v = g - BIG_ * im;
        vals[k] = v; mx = fmaxf(mx, v);
    }
    float s = 0.f;
    #pragma unroll
    for (int k = 0; k < K_; ++k) { vals[k] = expf(vals[k] - mx); s += vals[k]; }
    float invs = 1.f / s;
    #pragma unroll
    for (int k = 0; k < K_; ++k) dest[(size_t)t * K_ + k] = vals[k] * invs;
}

// ---------------- normalized_weights (XCD-swizzled) -------------------------
__global__ void k_normw(
    const float* __restrict__ nw, const float* __restrict__ dest,
    const int* __restrict__ rev, const int* __restrict__ adj,
    const int* __restrict__ num_nodes,
    float* __restrict__ normw)
{
    int j = blockIdx.x;
    int xcd = j & 7;
    int bb = xcd >> 1;
    int chunk = (j >> 3) * 2 + (xcd & 1);
    int ln = chunk * 256 + threadIdx.x;
    if (ln >= N_) return;
    int t = bb * N_ + ln;
    int pad = num_nodes[bb];
    float vals[K_]; float mx = -INFINITY;
    #pragma unroll
    for (int k = 0; k < K_; ++k) {
        size_t e = (size_t)t * K_ + k;
        float v = nw[e] * dest[(size_t)bb * NK_ + rev[e]];
        float m = (adj[e] == pad) ? 1.f : 0.f;
        v -= BIG_ * m;
        vals[k] = v; mx = fmaxf(mx, v);
    }
    float s = 0.f;
    #pragma unroll
    for (int k = 0; k < K_; ++k) { vals[k] = expf(vals[k] - mx); s += vals[k]; }
    float invs = 1.f / s;
    #pragma unroll
    for (int k = 0; k < K_; ++k)
        normw[(size_t)t * K_ + k] = vals[k] * invs;
}

// ---------------- flow prep + ITERATION 1 (XCD-swizzled) --------------------
__global__ void k_prep(
    const float* __restrict__ normw, const int* __restrict__ in_idx,
    const int* __restrict__ inv_adj, const int* __restrict__ num_nodes,
    const float* __restrict__ demands,
    float* __restrict__ supply, float* __restrict__ wgt, int* __restrict__ srcn,
    float* __restrict__ tot1)
{
    int j = blockIdx.x;
    int xcd = j & 7;
    int bb = xcd >> 1;
    int chunk = (j >> 3) * 2 + (xcd & 1);
    int ln = chunk * 256 + threadIdx.x;
    if (ln >= N_) return;
    int t = bb * N_ + ln;
    int pad = num_nodes[bb];
    float sup = fmaxf(-demands[t], 0.f);
    supply[t] = sup;
    float s1 = sup;
    #pragma unroll
    for (int k = 0; k < K_; ++k) {
        size_t e = (size_t)t * K_ + k;
        int jj = in_idx[e];
        bool valid = (inv_adj[e] != pad);
        float w = valid ? normw[(size_t)bb * NK_ + jj] : 0.f;
        int sn = bb * N_ + (jj >> 4);
        wgt[e] = w;
        srcn[e] = sn;
        s1 = fmaf(w, fmaxf(-demands[sn], 0.f), s1);
    }
    tot1[t] = s1;
}

// ---------------- one tot-space flow step (XCD-swizzled) --------------------
__global__ void k_flowT(
    const float* __restrict__ totIn, const float* __restrict__ wgt,
    const int* __restrict__ srcn, const float* __restrict__ supply,
    float* __restrict__ totOut)
{
    int j = blockIdx.x;
    int xcd = j & 7;
    int bb = xcd >> 1;
    int chunk = (j >> 3) * 2 + (xcd & 1);
    int ln = chunk * 256 + threadIdx.x;
    if (ln >= N_) return;
    int t = bb * N_ + ln;
    float s = supply[t];
    #pragma unroll
    for (int k = 0; k < K_; ++k) {
        size_t e = (size_t)t * K_ + k;
        s = fmaf(wgt[e], totIn[srcn[e]], s);
    }
    totOut[t] = s;
}

// ---------------- dual iterations + costs (+ final flow step inline) --------
__global__ __launch_bounds__(256) void k_dualred(
    const float* __restrict__ el, const float* __restrict__ dv,
    const int* __restrict__ adj, const int* __restrict__ num_nodes,
    const float* __restrict__ normw,
    const float* __restrict__ tot9, const float* __restrict__ wgt,
    const int* __restrict__ srcn, const float* __restrict__ supply,
    float* __restrict__ acc_out)
{
    int b = blockIdx.y;
    int ein = blockIdx.x * 256 + threadIdx.x;
    float c0 = 0.f, c1 = 0.f;
    if (ein < NK_) {                       // NK_ % 16 == 0: groups never straddle
        size_t e = (size_t)b * NK_ + ein;
        int pad = num_nodes[b];
        int node = b * N_ + (ein >> 4);
        int a = adj[e];
        float am = (a == pad) ? 0.f : 1.f;
        float dtr = (a == pad) ? 0.f : dv[(size_t)b * N_ + a];
        float d = dtr - am * dv[node];
        float l = el[e];
        float f = 0.f, ac = 0.f;
        #pragma unroll
        for (int it = 0; it < 10; ++it) {
            float g = 2.f * l * f + d;
            ac = 0.9f * ac + 0.01f * g;
            f = fmaxf(f - ac, 0.f) * am;
        }
        // inline flow step 10: this edge's k-slot contribution
        float part = wgt[e] * tot9[srcn[e]];
        #pragma unroll
        for (int m = 1; m < 16; m <<= 1) part += __shfl_xor(part, m, 64);
        float tot10 = supply[node] + part;
        float fl = normw[e] * tot10;
        c0 = l * fl * fl;          // flow_cost term
        c1 = l * f * f + d * f;    // dual flow term
    }
    #pragma unroll
    for (int m = 1; m < 64; m <<= 1) { c0 += __shfl_xor(c0, m, 64); c1 += __shfl_xor(c1, m, 64); }
    __shared__ float s0[4], s1[4];
    int wave = threadIdx.x >> 6, lane = threadIdx.x & 63;
    if (lane == 0) { s0[wave] = c0; s1[wave] = c1; }
    __syncthreads();
    if (threadIdx.x == 0) {
        atomicAdd(&acc_out[(b * 3 + 0) * 16], s0[0] + s0[1] + s0[2] + s0[3]);
        atomicAdd(&acc_out[(b * 3 + 1) * 16], s1[0] + s1[1] + s1[2] + s1[3]);
    }
}

// ---------------- finalize --------------------------------------------------
__global__ void k_final(const float* __restrict__ acc, float* __restrict__ out) {
    int b = threadIdx.x;
    if (b < B_)
        out[b] = acc[(b * 3 + 0) * 16] - acc[(b * 3 + 1) * 16] + acc[(b * 3 + 2) * 16];
}

extern "C" void kernel_launch(void* const* d_in, const int* in_sizes, int n_in,
                              void* d_out, int out_size, void* d_ws, size_t ws_size,
                              hipStream_t stream)
{
    const float* demands = (const float*)d_in[0];
    const float* feat    = (const float*)d_in[1];
    const float* el      = (const float*)d_in[2];
    const float* embed   = (const float*)d_in[3];
    const float* encW    = (const float*)d_in[4];
    const float* encb    = (const float*)d_in[5];
    const float* nbW     = (const float*)d_in[6];
    const float* Wq      = (const float*)d_in[7];
    const float* Wk      = (const float*)d_in[8];
    const float* Wv      = (const float*)d_in[9];
    const float* Wo      = (const float*)d_in[10];
    const float* gWz     = (const float*)d_in[11];
    const float* gUz     = (const float*)d_in[12];
    const float* gbz     = (const float*)d_in[13];
    const float* gWr     = (const float*)d_in[14];
    const float* gUr     = (const float*)d_in[15];
    const float* gbr     = (const float*)d_in[16];
    const float* gWh     = (const float*)d_in[17];
    const float* gUh     = (const float*)d_in[18];
    const float* gbh     = (const float*)d_in[19];
    const float* decW1   = (const float*)d_in[20];
    const float* decb1   = (const float*)d_in[21];
    const float* decW2   = (const float*)d_in[22];
    const float* decb2   = (const float*)d_in[23];
    const float* dualW1  = (const float*)d_in[24];
    const float* dualb1  = (const float*)d_in[25];
    const float* dualW2  = (const float*)d_in[26];
    const float* dualb2  = (const float*)d_in[27];
    const int* adj       = (const int*)d_in[28];
    const int* invadj    = (const int*)d_in[29];
    const int* neigh     = (const int*)d_in[30];
    const int* inidx     = (const int*)d_in[31];
    const int* revidx    = (const int*)d_in[32];
    const int* numn      = (const int*)d_in[33];

    // workspace (floats), ~24MB
    float* ws     = (float*)d_ws;
    float* h0     = ws;                   // 1,280,000
    float* h1     = ws + 1280000;         // 1,280,000 (ping-pong)
    float* nw     = ws + 2560000;         // 320,000
    float* dest   = ws + 2880000;         // 320,000
    float* normw  = ws + 3200000;         // 320,000
    float* wgt    = ws + 3520000;         // 320,000
    int*   srcn   = (int*)(ws + 3840000); // 320,000 ints
    float* totA   = ws + 4160000;         // 20,000
    float* totB   = ws + 4180000;         // 20,000
    float* supply = ws + 4200000;         // 20,000
    float* dv     = ws + 4220000;         // 20,000
    float* acc    = ws + 4240000;         // 192
    float* P      = ws + 4250000;         // 1,280,000 (edge projections)
    unsigned* pf  = (unsigned*)(ws + 5540000);        // 24,576 u32 pre-fragged W
    unsigned short* Pn16 = (unsigned short*)(ws + 5570000); // 640,000 u16 (bf16 P-nbr)

    // init: prepW (0-11), acc zero (12), encoder (13..5012)
    k_init<<<13 + BN_ / 4, 256, 0, stream>>>(Wq, nbW, Wk, Wv, Wo, gWz, gUz,
                                             gWr, gUr, gWh, gUh, decW1, pf, acc,
                                             embed, feat, encW, encb, h0);

    // layer 0: h0 -> h1 ; layer 1: h1 -> h0 (+ P/Pn16); XCD-swizzled grid
    k_layer<<<1280, 256, 0, stream>>>(h0, h1, neigh, numn, pf,
                                      gbz, gbr, gbh, P, Pn16, 0);
    k_layer<<<1280, 256, 0, stream>>>(h1, h0, neigh, numn, pf,
                                      gbz, gbr, gbh, P, Pn16, 1);
    float* h = h0;

    k_dec_dual<<<10500, 256, 0, stream>>>(P, Pn16, adj, decb1, decW2, decb2,
                                          numn, nw,
                                          h, dualW1, dualb1, dualW2, dualb2,
                                          demands, dv, acc);
    k_dest<<<80, 256, 0, stream>>>(nw, inidx, invadj, numn, dest);
    k_normw<<<80, 256, 0, stream>>>(nw, dest, revidx, adj, numn, normw);
    k_prep<<<80, 256, 0, stream>>>(normw, inidx, invadj, numn, demands,
                                   supply, wgt, srcn, totA);

    // totA holds tot1; 8 more launched iterations -> tot9 ends in totA
    float* cur = totA; float* nxt = totB;
    for (int it = 0; it < 8; ++it) {
        k_flowT<<<80, 256, 0, stream>>>(cur, wgt, srcn, supply, nxt);
        float* tmp = cur; cur = nxt; nxt = tmp;
    }

    // iteration 10 fused into dualred (16-lane group reduce)
    dim3 gred((NK_ + 255) / 256, B_);
    k_dualred<<<gred, 256, 0, stream>>>(el, dv, adj, numn, normw,
                                        cur, wgt, srcn, supply, acc);
    k_final<<<1, 64, 0, stream>>>(acc, (float*)d_out);
}